// Round 17
// baseline (750.209 us; speedup 1.0000x reference)
//
#include <hip/hip_runtime.h>

#define H_ 2048
#define E_ 32
#define KSEL 4
#define M_ 1408
#define I_ 8192
#define T_ 2048

typedef __bf16 bf16;
typedef bf16 bf16x8 __attribute__((ext_vector_type(8)));
typedef float f32x4 __attribute__((ext_vector_type(4)));
typedef unsigned short u16x8 __attribute__((ext_vector_type(8)));
typedef unsigned int u32x4 __attribute__((ext_vector_type(4)));

static __device__ __forceinline__ unsigned short bfb(float f) {
  return __builtin_bit_cast(unsigned short, (bf16)f);
}

static __device__ __forceinline__ void gload_lds16(const void* g, void* l) {
  __builtin_amdgcn_global_load_lds((const __attribute__((address_space(1))) void*)g,
                                   (__attribute__((address_space(3))) void*)l, 16, 0, 0);
}

static __device__ __forceinline__ float silu_f(float v) {
  return v / (1.f + __expf(-v));
}

static __device__ __forceinline__ void wave_argmax(float& v, int& vi) {
  #pragma unroll
  for (int off = 32; off >= 1; off >>= 1) {
    float ov = __shfl_xor(v, off);
    int   oi = __shfl_xor(vi, off);
    if (ov > v || (ov == v && oi < vi)) { v = ov; vi = oi; }
  }
}

// ---------------- prep: zero counts ----------------
__global__ __launch_bounds__(64) void prep_k(int* __restrict__ counts) {
  if (threadIdx.x < E_) counts[threadIdx.x] = 0;
}

// ---------------- combine: out = 4 routed-slot slices + 2 shared-kz slices ----------------
__global__ __launch_bounds__(256) void combine_k(const float* __restrict__ sc,
                                                 const float* __restrict__ sc2,
                                                 float* __restrict__ out) {
  size_t i = ((size_t)blockIdx.x * 256 + threadIdx.x) * 4;
  int t = (int)(i >> 11);
  int h = (int)(i & 2047);
  const float* s = sc + (size_t)(t * 4) * H_ + h;
  float4 a = *(const float4*)(s);
  float4 b = *(const float4*)(s + H_);
  float4 c = *(const float4*)(s + 2 * H_);
  float4 d = *(const float4*)(s + 3 * H_);
  float4 o;
  o.x = a.x + b.x + c.x + d.x;
  o.y = a.y + b.y + c.y + d.y;
  o.z = a.z + b.z + c.z + d.z;
  o.w = a.w + b.w + c.w + d.w;
  #pragma unroll
  for (int kz = 0; kz < 2; ++kz) {
    float4 v = *(const float4*)(sc2 + (size_t)kz * T_ * H_ + i);
    o.x += v.x; o.y += v.y; o.z += v.z; o.w += v.w;
  }
  *(float4*)(out + i) = o;
}

// ---------------- router: x->bf16 cvt + logits (fp32) + top-4 + softmax + expert lists ----------------
__global__ __launch_bounds__(64) void router_k(const float* __restrict__ x, const float* __restrict__ gw,
                                               float* __restrict__ logits, int* __restrict__ counts,
                                               int* __restrict__ tlist, float* __restrict__ wlist,
                                               unsigned short* __restrict__ xb) {
  int t = blockIdx.x;
  int l = threadIdx.x;

  // fold cvt: convert x[t] -> xb[t], coalesced 512-element rounds
  {
    const float* xrow = x + (size_t)t * H_;
    unsigned short* xbrow = xb + (size_t)t * H_;
    #pragma unroll
    for (int j = 0; j < 4; ++j) {
      int base = j * 512 + l * 8;
      float4 a = *(const float4*)(xrow + base);
      float4 b = *(const float4*)(xrow + base + 4);
      u16x8 o;
      o[0]=bfb(a.x); o[1]=bfb(a.y); o[2]=bfb(a.z); o[3]=bfb(a.w);
      o[4]=bfb(b.x); o[5]=bfb(b.y); o[6]=bfb(b.z); o[7]=bfb(b.w);
      *(u16x8*)(xbrow + base) = o;
    }
  }

  int e = l & 31;
  int half = l >> 5;
  const float* xr = x + (size_t)t * H_ + half * (H_/2);
  const float* g  = gw + (size_t)(half * (H_/2)) * E_ + e;
  float a0=0.f, a1=0.f, a2=0.f, a3=0.f;
  for (int h = 0; h < H_/2; h += 4) {
    a0 = fmaf(xr[h],   g[(size_t)h*E_],     a0);
    a1 = fmaf(xr[h+1], g[(size_t)(h+1)*E_], a1);
    a2 = fmaf(xr[h+2], g[(size_t)(h+2)*E_], a2);
    a3 = fmaf(xr[h+3], g[(size_t)(h+3)*E_], a3);
  }
  float acc = (a0+a1)+(a2+a3);
  acc += __shfl_xor(acc, 32);
  if (l < E_) logits[(size_t)t*E_ + l] = acc;

  float cur = (l < E_) ? acc : -INFINITY;
  int myidx = (l < E_) ? e : 1000;
  float tv0,tv1,tv2,tv3; int ti0,ti1,ti2,ti3;
  { float v=cur; int vi=myidx; wave_argmax(v,vi); tv0=v; ti0=vi; if (myidx==vi) cur=-INFINITY; }
  { float v=cur; int vi=myidx; wave_argmax(v,vi); tv1=v; ti1=vi; if (myidx==vi) cur=-INFINITY; }
  { float v=cur; int vi=myidx; wave_argmax(v,vi); tv2=v; ti2=vi; if (myidx==vi) cur=-INFINITY; }
  { float v=cur; int vi=myidx; wave_argmax(v,vi); tv3=v; ti3=vi; }
  float w0 = 1.f;
  float w1 = __expf(tv1 - tv0);
  float w2 = __expf(tv2 - tv0);
  float w3 = __expf(tv3 - tv0);
  float inv = 1.f / (w0+w1+w2+w3);
  if (l < KSEL) {
    float myw = ((l==0)?w0:(l==1)?w1:(l==2)?w2:w3) * inv;
    int   myi = ((l==0)?ti0:(l==1)?ti1:(l==2)?ti2:ti3);
    int pos = atomicAdd(&counts[myi], 1);
    tlist[myi*T_ + pos] = (t << 2) | l;
    wlist[myi*T_ + pos] = myw;
  }
}

// ---------------- GEMM body (r13-verified: BK=64, BM=128, BN=64, 2-barrier) ----------------
// lst/wl/Bp passed pre-offset for routed modes. nrows=T_ for dense.
template<int MODE, int KDIM, int NDIM, int ASTR, int KSPLIT>
__device__ __forceinline__ void gemm_body(
    char* __restrict__ smem, int mt, int nt, int kz, int nrows,
    const bf16* __restrict__ A, const float* __restrict__ Bp,
    bf16* __restrict__ Cb, float* __restrict__ Cf,
    const int* __restrict__ lst, const float* __restrict__ wl)
{
  char* As = smem;            // 128 rows x 64 k bf16 (128B rows, 8 slots, swizzled)
  char* Bs = smem + 16384;    // slot-major [8][64][16B]
  const int tid = threadIdx.x;
  const int mrow0 = mt*128, ncol0 = nt*64;

  const bf16* abase[4];
  int aoffs[4];
  #pragma unroll
  for (int c = 0; c < 4; ++c) {
    int lidx = c*256 + tid;
    int row  = lidx >> 3;
    int slot = lidx & 7;
    aoffs[c] = (slot ^ (row & 7)) * 8;
    int ri = mrow0 + row;
    if constexpr (MODE == 2) {
      int tt = (ri < nrows) ? (lst[ri] >> 2) : 0;
      abase[c] = A + (size_t)tt * ASTR;
    } else if constexpr (MODE == 3) {
      int ar = (ri < nrows) ? lst[ri] : 0;
      abase[c] = A + (size_t)ar * ASTR;
    } else {
      abase[c] = A + (size_t)ri * ASTR;
    }
  }

  const int bn = tid & 63;
  const int bq = tid >> 6;
  const float* bsrc0 = Bp + (size_t)(bq * 16) * NDIM + ncol0 + bn;
  char* const bdst = Bs + (bq*2)*1024 + bn*16;

  const int l  = tid & 63;
  const int wv = tid >> 6;
  const int wr = wv >> 1, wc = wv & 1;
  const int ss = l >> 4;

  f32x4 acc[4][2] = {};

  constexpr int ITERS = KDIM / 64 / KSPLIT;
  static_assert(ITERS % 2 == 0, "K-loop is 2-unrolled");
  const int kt0 = kz * ITERS;
  const int ktend = kt0 + ITERS;

  float vA[16], vB[16];   // constant-indexed only (full unroll) -> registers

#define LOADB(P, KT) do {                                            \
    const float* bs_ = bsrc0 + (size_t)((KT) * 64) * NDIM;           \
    _Pragma("unroll")                                                \
    for (int j = 0; j < 16; ++j) P[j] = bs_[(size_t)j * NDIM];       \
  } while (0)

#define WRITEB(P) do {                                               \
    u32x4 lo_, hi_;                                                  \
    _Pragma("unroll")                                                \
    for (int j = 0; j < 4; ++j) {                                    \
      lo_[j] = (unsigned)bfb(P[2*j])   | ((unsigned)bfb(P[2*j+1]) << 16); \
      hi_[j] = (unsigned)bfb(P[8+2*j]) | ((unsigned)bfb(P[8+2*j+1]) << 16); \
    }                                                                \
    *(u32x4*)(bdst)        = lo_;                                    \
    *(u32x4*)(bdst + 1024) = hi_;                                    \
  } while (0)

#define MFMA_HALF(S) do {                                            \
    bf16x8 af[4], bfr[2];                                            \
    const int ks = (S)*4 + ss;                                       \
    _Pragma("unroll")                                                \
    for (int mf = 0; mf < 4; ++mf) {                                 \
      int r = wr*64 + mf*16 + (l & 15);                              \
      af[mf] = *(const bf16x8*)(As + r*128 + ((ks ^ (r & 7)) << 4)); \
    }                                                                \
    _Pragma("unroll")                                                \
    for (int nf = 0; nf < 2; ++nf) {                                 \
      int c = wc*32 + nf*16 + (l & 15);                              \
      bfr[nf] = *(const bf16x8*)(Bs + ks*1024 + c*16);               \
    }                                                                \
    _Pragma("unroll")                                                \
    for (int mf = 0; mf < 4; ++mf)                                   \
      _Pragma("unroll")                                              \
      for (int nf = 0; nf < 2; ++nf)                                 \
        acc[mf][nf] = __builtin_amdgcn_mfma_f32_16x16x32_bf16(af[mf], bfr[nf], acc[mf][nf], 0, 0, 0); \
  } while (0)

#define MFMA_PHASE() do { MFMA_HALF(0); MFMA_HALF(1); } while (0)

#define ADMA(KT) do {                                                \
    _Pragma("unroll")                                                \
    for (int c = 0; c < 4; ++c)                                      \
      gload_lds16(abase[c] + (KT)*64 + aoffs[c], As + (c*256 + tid)*16); \
  } while (0)

  LOADB(vA, kt0);
  for (int kt = kt0; kt < ktend; kt += 2) {
    __syncthreads();
    ADMA(kt);
    WRITEB(vA);
    __syncthreads();
    LOADB(vB, kt + 1);           // flies during MFMA phase
    MFMA_PHASE();

    __syncthreads();
    ADMA(kt + 1);
    WRITEB(vB);
    __syncthreads();
    if (kt + 2 < ktend) LOADB(vA, kt + 2);   // flies during MFMA phase
    MFMA_PHASE();
  }

#undef LOADB
#undef WRITEB
#undef MFMA_HALF
#undef MFMA_PHASE
#undef ADMA

  // epilogue — C/D layout: row=(l>>4)*4+j, col=l&15 within each 16x16 frag
  #pragma unroll
  for (int mf = 0; mf < 4; ++mf) {
    #pragma unroll
    for (int j = 0; j < 4; ++j) {
      const int rloc = wr*64 + mf*16 + (l >> 4)*4 + j;
      const int grow = mrow0 + rloc;
      if constexpr (MODE == 0) {
        #pragma unroll
        for (int nf = 0; nf < 2; ++nf) {
          int col = ncol0 + wc*32 + nf*16 + (l & 15);
          Cb[(size_t)grow * NDIM + col] = (bf16)silu_f(acc[mf][nf][j]);
        }
      } else if constexpr (MODE == 1) {
        float* dst = Cf + (size_t)kz * T_ * H_;
        #pragma unroll
        for (int nf = 0; nf < 2; ++nf) {
          int col = ncol0 + wc*32 + nf*16 + (l & 15);
          dst[(size_t)grow * NDIM + col] = acc[mf][nf][j];
        }
      } else if constexpr (MODE == 2) {
        if (grow < nrows) {
          int entry = lst[grow];
          float wg = wl[grow];
          #pragma unroll
          for (int nf = 0; nf < 2; ++nf) {
            int col = ncol0 + wc*32 + nf*16 + (l & 15);
            Cb[(size_t)entry * NDIM + col] = (bf16)(silu_f(acc[mf][nf][j]) * wg);
          }
        }
      } else {
        if (grow < nrows) {
          int entry = lst[grow];
          #pragma unroll
          for (int nf = 0; nf < 2; ++nf) {
            int col = ncol0 + wc*32 + nf*16 + (l & 15);
            Cf[(size_t)entry * H_ + col] = acc[mf][nf][j];
          }
        }
      }
    }
  }
}

// ---------------- fused dispatch A: gemm2 (expert-up) ∥ gemm0 (shared-up) ----------------
// x < 1408: routed expert-up (NT=22, live mt-pair innermost swizzle, y=mt group).
// x >= 1408: dense shared-up tile t=(x-1408)*8+y in [0,2048), XCD-chunked swizzle.
__global__ __launch_bounds__(256) void fusedA_k(
    const bf16* __restrict__ xb, const float* __restrict__ w1, const float* __restrict__ ws1,
    bf16* __restrict__ act, bf16* __restrict__ y1,
    const int* __restrict__ tlist, const float* __restrict__ wlist, const int* __restrict__ counts)
{
  __shared__ __align__(16) char smem[24576];
  if (blockIdx.x < 1408) {
    constexpr int NT = M_ / 64;              // 22
    constexpr int NWG = NT * E_ * 2;         // 1408
    constexpr int CPX = NWG / 8;
    int id = blockIdx.x;
    int lg = (id & 7) * CPX + (id >> 3);
    int bit = lg & 1;
    int en  = lg >> 1;
    int e  = en / NT;
    int nt = en % NT;
    int mt = (blockIdx.y == 0) ? bit : (2 + 2*((int)blockIdx.y - 1) + bit);
    int nrows = counts[e];
    if (mt * 128 >= nrows) return;
    gemm_body<2, 2048, M_, 2048, 1>(smem, mt, nt, 0, nrows,
        xb, w1 + (size_t)e * 2048 * M_, act, nullptr, tlist + e*T_, wlist + e*T_);
  } else {
    int t = ((int)blockIdx.x - 1408) * 8 + (int)blockIdx.y;   // [0,2048)
    constexpr int CPX = 2048 / 8;
    int lg = (t & 7) * CPX + (t >> 3);
    int mt = lg & 15;
    int nt = lg >> 4;                        // [0,128)
    gemm_body<0, 2048, I_, 2048, 1>(smem, mt, nt, 0, T_,
        xb, ws1, y1, nullptr, nullptr, nullptr);
  }
}

// ---------------- fused dispatch B: gemm3 (expert-down) ∥ gemm1 (shared-down) ----------------
// x < 2048: routed expert-down (NT=32). x >= 2048: dense shared-down split-K=2,
// id=(x-2048)*8+y in [0,1024), kz=id&1, sub=id>>1 with XCD-chunked swizzle.
__global__ __launch_bounds__(256) void fusedB_k(
    const bf16* __restrict__ y1, const float* __restrict__ ws2,
    const bf16* __restrict__ act, const float* __restrict__ w2,
    float* __restrict__ scratch2, float* __restrict__ scratch,
    const int* __restrict__ tlist, const int* __restrict__ counts)
{
  __shared__ __align__(16) char smem[24576];
  if (blockIdx.x < 2048) {
    constexpr int NT = H_ / 64;              // 32
    constexpr int NWG = NT * E_ * 2;         // 2048
    constexpr int CPX = NWG / 8;
    int id = blockIdx.x;
    int lg = (id & 7) * CPX + (id >> 3);
    int bit = lg & 1;
    int en  = lg >> 1;
    int e  = en / NT;
    int nt = en % NT;
    int mt = (blockIdx.y == 0) ? bit : (2 + 2*((int)blockIdx.y - 1) + bit);
    int nrows = counts[e];
    if (mt * 128 >= nrows) return;
    gemm_body<3, M_, H_, M_, 1>(smem, mt, nt, 0, nrows,
        act, w2 + (size_t)e * M_ * H_, nullptr, scratch, tlist + e*T_, nullptr);
  } else {
    int id = ((int)blockIdx.x - 2048) * 8 + (int)blockIdx.y;  // [0,1024)
    int kz  = id & 1;
    int sub = id >> 1;                       // [0,512)
    constexpr int CPX = 512 / 8;
    int lg = (sub & 7) * CPX + (sub >> 3);
    int mt = lg & 15;
    int nt = lg >> 4;                        // [0,32)
    gemm_body<1, I_, H_, I_, 2>(smem, mt, nt, kz, T_,
        y1, ws2, nullptr, scratch2, nullptr, nullptr);
  }
}

extern "C" void kernel_launch(void* const* d_in, const int* in_sizes, int n_in,
                              void* d_out, int out_size, void* d_ws, size_t ws_size,
                              hipStream_t stream) {
  const float* x   = (const float*)d_in[0];
  const float* gw  = (const float*)d_in[1];
  const float* w1  = (const float*)d_in[2];
  const float* w2  = (const float*)d_in[3];
  const float* ws1 = (const float*)d_in[4];
  const float* ws2 = (const float*)d_in[5];
  float* out    = (float*)d_out;
  float* logits = out + (size_t)T_ * H_;

  char* ws = (char*)d_ws;
  const size_t off_xb   = 0;
  const size_t off_y1   = off_xb  + (size_t)T_ * H_ * 2;
  const size_t off_act  = off_y1  + (size_t)T_ * I_ * 2;
  const size_t off_cnt  = off_act + (size_t)T_ * 4 * M_ * 2;
  const size_t off_tl   = off_cnt + 256;
  const size_t off_wl   = off_tl  + (size_t)E_ * T_ * 4;
  const size_t off_sc   = off_wl  + (size_t)E_ * T_ * 4;              // fp32 [4T][H]
  const size_t off_sc2  = off_sc  + (size_t)T_ * 4 * H_ * 4;          // fp32 [2][T][H]

  const bf16* xb = (const bf16*)(ws + off_xb);
  bf16* y1  = (bf16*)(ws + off_y1);
  bf16* act = (bf16*)(ws + off_act);
  int*  counts = (int*)(ws + off_cnt);
  int*  tlist  = (int*)(ws + off_tl);
  float* wlist = (float*)(ws + off_wl);
  float* scratch  = (float*)(ws + off_sc);
  float* scratch2 = (float*)(ws + off_sc2);

  prep_k<<<1, 64, 0, stream>>>(counts);
  router_k<<<T_, 64, 0, stream>>>(x, gw, logits, counts, tlist, wlist,
                                  (unsigned short*)(ws + off_xb));

  fusedA_k<<<dim3(1408 + 256, 8), 256, 0, stream>>>(
      xb, w1, ws1, act, y1, tlist, wlist, counts);
  fusedB_k<<<dim3(2048 + 128, 8), 256, 0, stream>>>(
      y1, ws2, act, w2, scratch2, scratch, tlist, counts);
  combine_k<<<4096, 256, 0, stream>>>(scratch, scratch2, out);
}

// Round 18
// 721.217 us; speedup vs baseline: 1.0402x; 1.0402x over previous
//
#include <hip/hip_runtime.h>

#define H_ 2048
#define E_ 32
#define KSEL 4
#define M_ 1408
#define I_ 8192
#define T_ 2048

typedef __bf16 bf16;
typedef bf16 bf16x8 __attribute__((ext_vector_type(8)));
typedef float f32x4 __attribute__((ext_vector_type(4)));
typedef unsigned short u16x8 __attribute__((ext_vector_type(8)));
typedef unsigned int u32x4 __attribute__((ext_vector_type(4)));

static __device__ __forceinline__ unsigned short bfb(float f) {
  return __builtin_bit_cast(unsigned short, (bf16)f);
}

static __device__ __forceinline__ void gload_lds16(const void* g, void* l) {
  __builtin_amdgcn_global_load_lds((const __attribute__((address_space(1))) void*)g,
                                   (__attribute__((address_space(3))) void*)l, 16, 0, 0);
}

static __device__ __forceinline__ float silu_f(float v) {
  return v / (1.f + __expf(-v));
}

static __device__ __forceinline__ void wave_argmax(float& v, int& vi) {
  #pragma unroll
  for (int off = 32; off >= 1; off >>= 1) {
    float ov = __shfl_xor(v, off);
    int   oi = __shfl_xor(vi, off);
    if (ov > v || (ov == v && oi < vi)) { v = ov; vi = oi; }
  }
}

// ---------------- prep: zero counts ----------------
__global__ __launch_bounds__(64) void prep_k(int* __restrict__ counts) {
  if (threadIdx.x < E_) counts[threadIdx.x] = 0;
}

// ---------------- transpose+convert: src fp32 [K,N] -> dst bf16 [N,K] (r2-verified) ----------------
__global__ __launch_bounds__(256) void tconv_k(const float* __restrict__ src, bf16* __restrict__ dst,
                                               int K, int N) {
  __shared__ bf16 lt[64][66];
  const int t = threadIdx.x;
  const int k0 = blockIdx.x * 64, n0 = blockIdx.y * 64;
  #pragma unroll
  for (int p = 0; p < 4; ++p) {
    int r = p * 16 + (t >> 4);
    int c = (t & 15) * 4;
    float4 v = *(const float4*)(src + (size_t)(k0 + r) * N + n0 + c);
    lt[c+0][r] = (bf16)v.x; lt[c+1][r] = (bf16)v.y;
    lt[c+2][r] = (bf16)v.z; lt[c+3][r] = (bf16)v.w;
  }
  __syncthreads();
  #pragma unroll
  for (int q = 0; q < 2; ++q) {
    int n  = q * 32 + (t >> 3);
    int ks = (t & 7) * 8;
    bf16x8 o;
    #pragma unroll
    for (int j = 0; j < 8; ++j) o[j] = lt[n][ks + j];
    *(bf16x8*)(dst + (size_t)(n0 + n) * K + k0 + ks) = o;
  }
}

// ---------------- combine: out = 4 routed-slot slices + 2 shared-kz slices ----------------
__global__ __launch_bounds__(256) void combine_k(const float* __restrict__ sc,
                                                 const float* __restrict__ sc2,
                                                 float* __restrict__ out) {
  size_t i = ((size_t)blockIdx.x * 256 + threadIdx.x) * 4;
  int t = (int)(i >> 11);
  int h = (int)(i & 2047);
  const float* s = sc + (size_t)(t * 4) * H_ + h;
  float4 a = *(const float4*)(s);
  float4 b = *(const float4*)(s + H_);
  float4 c = *(const float4*)(s + 2 * H_);
  float4 d = *(const float4*)(s + 3 * H_);
  float4 o;
  o.x = a.x + b.x + c.x + d.x;
  o.y = a.y + b.y + c.y + d.y;
  o.z = a.z + b.z + c.z + d.z;
  o.w = a.w + b.w + c.w + d.w;
  #pragma unroll
  for (int kz = 0; kz < 2; ++kz) {
    float4 v = *(const float4*)(sc2 + (size_t)kz * T_ * H_ + i);
    o.x += v.x; o.y += v.y; o.z += v.z; o.w += v.w;
  }
  *(float4*)(out + i) = o;
}

// ---------------- router: x->bf16 cvt + logits (fp32) + top-4 + softmax + expert lists ----------------
__global__ __launch_bounds__(64) void router_k(const float* __restrict__ x, const float* __restrict__ gw,
                                               float* __restrict__ logits, int* __restrict__ counts,
                                               int* __restrict__ tlist, float* __restrict__ wlist,
                                               unsigned short* __restrict__ xb) {
  int t = blockIdx.x;
  int l = threadIdx.x;

  {
    const float* xrow = x + (size_t)t * H_;
    unsigned short* xbrow = xb + (size_t)t * H_;
    #pragma unroll
    for (int j = 0; j < 4; ++j) {
      int base = j * 512 + l * 8;
      float4 a = *(const float4*)(xrow + base);
      float4 b = *(const float4*)(xrow + base + 4);
      u16x8 o;
      o[0]=bfb(a.x); o[1]=bfb(a.y); o[2]=bfb(a.z); o[3]=bfb(a.w);
      o[4]=bfb(b.x); o[5]=bfb(b.y); o[6]=bfb(b.z); o[7]=bfb(b.w);
      *(u16x8*)(xbrow + base) = o;
    }
  }

  int e = l & 31;
  int half = l >> 5;
  const float* xr = x + (size_t)t * H_ + half * (H_/2);
  const float* g  = gw + (size_t)(half * (H_/2)) * E_ + e;
  float a0=0.f, a1=0.f, a2=0.f, a3=0.f;
  for (int h = 0; h < H_/2; h += 4) {
    a0 = fmaf(xr[h],   g[(size_t)h*E_],     a0);
    a1 = fmaf(xr[h+1], g[(size_t)(h+1)*E_], a1);
    a2 = fmaf(xr[h+2], g[(size_t)(h+2)*E_], a2);
    a3 = fmaf(xr[h+3], g[(size_t)(h+3)*E_], a3);
  }
  float acc = (a0+a1)+(a2+a3);
  acc += __shfl_xor(acc, 32);
  if (l < E_) logits[(size_t)t*E_ + l] = acc;

  float cur = (l < E_) ? acc : -INFINITY;
  int myidx = (l < E_) ? e : 1000;
  float tv0,tv1,tv2,tv3; int ti0,ti1,ti2,ti3;
  { float v=cur; int vi=myidx; wave_argmax(v,vi); tv0=v; ti0=vi; if (myidx==vi) cur=-INFINITY; }
  { float v=cur; int vi=myidx; wave_argmax(v,vi); tv1=v; ti1=vi; if (myidx==vi) cur=-INFINITY; }
  { float v=cur; int vi=myidx; wave_argmax(v,vi); tv2=v; ti2=vi; if (myidx==vi) cur=-INFINITY; }
  { float v=cur; int vi=myidx; wave_argmax(v,vi); tv3=v; ti3=vi; }
  float w0 = 1.f;
  float w1 = __expf(tv1 - tv0);
  float w2 = __expf(tv2 - tv0);
  float w3 = __expf(tv3 - tv0);
  float inv = 1.f / (w0+w1+w2+w3);
  if (l < KSEL) {
    float myw = ((l==0)?w0:(l==1)?w1:(l==2)?w2:w3) * inv;
    int   myi = ((l==0)?ti0:(l==1)?ti1:(l==2)?ti2:ti3);
    int pos = atomicAdd(&counts[myi], 1);
    tlist[myi*T_ + pos] = (t << 2) | l;
    wlist[myi*T_ + pos] = myw;
  }
}

// ---------------- GEMM body (BK=64, BM=128, BN=64, r13-verified 2-barrier drain) ----------------
// Dense modes (0,1): BOTH operands bf16 via global_load_lds (Btp = bf16 [N,K]),
// same slot^(row&7) both-sides swizzle for A and B; loop = bar; DMA; bar; MFMA.
// Routed modes (2,3): B reg-staged from fp32 [K,N] with T14 prefetch (r13 loop).
template<int MODE, int KDIM, int NDIM, int ASTR, int KSPLIT>
__device__ __forceinline__ void gemm_body(
    char* __restrict__ smem, int mt, int nt, int kz, int nrows,
    const bf16* __restrict__ A, const float* __restrict__ Bp, const bf16* __restrict__ Btp,
    bf16* __restrict__ Cb, float* __restrict__ Cf,
    const int* __restrict__ lst, const float* __restrict__ wl)
{
  char* As = smem;            // 128 rows x 64 k bf16 (128B rows, 8 slots, swizzled)
  char* Bs = smem + 16384;    // dense: 64 rows x 128B (swizzled) | routed: slot-major [8][64][16B]
  const int tid = threadIdx.x;
  const int mrow0 = mt*128, ncol0 = nt*64;

  const bf16* abase[4];
  int aoffs[4];
  #pragma unroll
  for (int c = 0; c < 4; ++c) {
    int lidx = c*256 + tid;
    int row  = lidx >> 3;
    int slot = lidx & 7;
    aoffs[c] = (slot ^ (row & 7)) * 8;
    int ri = mrow0 + row;
    if constexpr (MODE == 2) {
      int tt = (ri < nrows) ? (lst[ri] >> 2) : 0;
      abase[c] = A + (size_t)tt * ASTR;
    } else if constexpr (MODE == 3) {
      int ar = (ri < nrows) ? lst[ri] : 0;
      abase[c] = A + (size_t)ar * ASTR;
    } else {
      abase[c] = A + (size_t)ri * ASTR;
    }
  }

  // dense B DMA bases (bf16 [N,K])
  const bf16* bbaseB[2];
  int boffs[2];
  if constexpr (MODE <= 1) {
    #pragma unroll
    for (int c = 0; c < 2; ++c) {
      int lidx = c*256 + tid;
      int row  = lidx >> 3;
      int slot = lidx & 7;
      boffs[c] = (slot ^ (row & 7)) * 8;
      bbaseB[c] = Btp + (size_t)(ncol0 + row) * KDIM;
    }
  }

  // routed B reg-staging partition
  const int bn = tid & 63;
  const int bq = tid >> 6;
  const float* bsrc0 = Bp + (size_t)(bq * 16) * NDIM + ncol0 + bn;
  char* const bdst = Bs + (bq*2)*1024 + bn*16;

  const int l  = tid & 63;
  const int wv = tid >> 6;
  const int wr = wv >> 1, wc = wv & 1;
  const int ss = l >> 4;

  f32x4 acc[4][2] = {};

  constexpr int ITERS = KDIM / 64 / KSPLIT;
  static_assert(ITERS % 2 == 0, "K-loop is 2-unrolled");
  const int kt0 = kz * ITERS;
  const int ktend = kt0 + ITERS;

  float vA[16], vB[16];   // constant-indexed only (full unroll) -> registers

#define LOADB(P, KT) do {                                            \
    const float* bs_ = bsrc0 + (size_t)((KT) * 64) * NDIM;           \
    _Pragma("unroll")                                                \
    for (int j = 0; j < 16; ++j) P[j] = bs_[(size_t)j * NDIM];       \
  } while (0)

#define WRITEB(P) do {                                               \
    u32x4 lo_, hi_;                                                  \
    _Pragma("unroll")                                                \
    for (int j = 0; j < 4; ++j) {                                    \
      lo_[j] = (unsigned)bfb(P[2*j])   | ((unsigned)bfb(P[2*j+1]) << 16); \
      hi_[j] = (unsigned)bfb(P[8+2*j]) | ((unsigned)bfb(P[8+2*j+1]) << 16); \
    }                                                                \
    *(u32x4*)(bdst)        = lo_;                                    \
    *(u32x4*)(bdst + 1024) = hi_;                                    \
  } while (0)

#define MFMA_HALF(S) do {                                            \
    bf16x8 af[4], bfr[2];                                            \
    const int ks = (S)*4 + ss;                                       \
    _Pragma("unroll")                                                \
    for (int mf = 0; mf < 4; ++mf) {                                 \
      int r = wr*64 + mf*16 + (l & 15);                              \
      af[mf] = *(const bf16x8*)(As + r*128 + ((ks ^ (r & 7)) << 4)); \
    }                                                                \
    _Pragma("unroll")                                                \
    for (int nf = 0; nf < 2; ++nf) {                                 \
      int c = wc*32 + nf*16 + (l & 15);                              \
      if constexpr (MODE <= 1)                                       \
        bfr[nf] = *(const bf16x8*)(Bs + c*128 + ((ks ^ (c & 7)) << 4)); \
      else                                                           \
        bfr[nf] = *(const bf16x8*)(Bs + ks*1024 + c*16);             \
    }                                                                \
    _Pragma("unroll")                                                \
    for (int mf = 0; mf < 4; ++mf)                                   \
      _Pragma("unroll")                                              \
      for (int nf = 0; nf < 2; ++nf)                                 \
        acc[mf][nf] = __builtin_amdgcn_mfma_f32_16x16x32_bf16(af[mf], bfr[nf], acc[mf][nf], 0, 0, 0); \
  } while (0)

#define MFMA_PHASE() do { MFMA_HALF(0); MFMA_HALF(1); } while (0)

#define ADMA(KT) do {                                                \
    _Pragma("unroll")                                                \
    for (int c = 0; c < 4; ++c)                                      \
      gload_lds16(abase[c] + (KT)*64 + aoffs[c], As + (c*256 + tid)*16); \
  } while (0)

#define BDMA(KT) do {                                                \
    _Pragma("unroll")                                                \
    for (int c = 0; c < 2; ++c)                                      \
      gload_lds16(bbaseB[c] + (KT)*64 + boffs[c], Bs + (c*256 + tid)*16); \
  } while (0)

  if constexpr (MODE <= 1) {
    for (int kt = kt0; kt < ktend; ++kt) {
      __syncthreads();
      ADMA(kt);
      BDMA(kt);
      __syncthreads();
      MFMA_PHASE();
    }
  } else {
    LOADB(vA, kt0);
    for (int kt = kt0; kt < ktend; kt += 2) {
      __syncthreads();
      ADMA(kt);
      WRITEB(vA);
      __syncthreads();
      LOADB(vB, kt + 1);           // flies during MFMA phase
      MFMA_PHASE();

      __syncthreads();
      ADMA(kt + 1);
      WRITEB(vB);
      __syncthreads();
      if (kt + 2 < ktend) LOADB(vA, kt + 2);   // flies during MFMA phase
      MFMA_PHASE();
    }
  }

#undef LOADB
#undef WRITEB
#undef MFMA_HALF
#undef MFMA_PHASE
#undef ADMA
#undef BDMA

  // epilogue — C/D layout: row=(l>>4)*4+j, col=l&15 within each 16x16 frag
  #pragma unroll
  for (int mf = 0; mf < 4; ++mf) {
    #pragma unroll
    for (int j = 0; j < 4; ++j) {
      const int rloc = wr*64 + mf*16 + (l >> 4)*4 + j;
      const int grow = mrow0 + rloc;
      if constexpr (MODE == 0) {
        #pragma unroll
        for (int nf = 0; nf < 2; ++nf) {
          int col = ncol0 + wc*32 + nf*16 + (l & 15);
          Cb[(size_t)grow * NDIM + col] = (bf16)silu_f(acc[mf][nf][j]);
        }
      } else if constexpr (MODE == 1) {
        float* dst = Cf + (size_t)kz * T_ * H_;
        #pragma unroll
        for (int nf = 0; nf < 2; ++nf) {
          int col = ncol0 + wc*32 + nf*16 + (l & 15);
          dst[(size_t)grow * NDIM + col] = acc[mf][nf][j];
        }
      } else if constexpr (MODE == 2) {
        if (grow < nrows) {
          int entry = lst[grow];
          float wg = wl[grow];
          #pragma unroll
          for (int nf = 0; nf < 2; ++nf) {
            int col = ncol0 + wc*32 + nf*16 + (l & 15);
            Cb[(size_t)entry * NDIM + col] = (bf16)(silu_f(acc[mf][nf][j]) * wg);
          }
        }
      } else {
        if (grow < nrows) {
          int entry = lst[grow];
          #pragma unroll
          for (int nf = 0; nf < 2; ++nf) {
            int col = ncol0 + wc*32 + nf*16 + (l & 15);
            Cf[(size_t)entry * H_ + col] = acc[mf][nf][j];
          }
        }
      }
    }
  }
}

// ---------------- fused dispatch A: gemm2 (expert-up) ∥ gemm0 (shared-up) ----------------
__global__ __launch_bounds__(256) void fusedA_k(
    const bf16* __restrict__ xb, const float* __restrict__ w1, const bf16* __restrict__ ws1t,
    bf16* __restrict__ act, bf16* __restrict__ y1,
    const int* __restrict__ tlist, const float* __restrict__ wlist, const int* __restrict__ counts)
{
  __shared__ __align__(16) char smem[24576];
  if (blockIdx.x < 1408) {
    constexpr int NT = M_ / 64;              // 22
    constexpr int NWG = NT * E_ * 2;         // 1408
    constexpr int CPX = NWG / 8;
    int id = blockIdx.x;
    int lg = (id & 7) * CPX + (id >> 3);
    int bit = lg & 1;
    int en  = lg >> 1;
    int e  = en / NT;
    int nt = en % NT;
    int mt = (blockIdx.y == 0) ? bit : (2 + 2*((int)blockIdx.y - 1) + bit);
    int nrows = counts[e];
    if (mt * 128 >= nrows) return;
    gemm_body<2, 2048, M_, 2048, 1>(smem, mt, nt, 0, nrows,
        xb, w1 + (size_t)e * 2048 * M_, nullptr, act, nullptr, tlist + e*T_, wlist + e*T_);
  } else {
    int t = ((int)blockIdx.x - 1408) * 8 + (int)blockIdx.y;   // [0,2048)
    constexpr int CPX = 2048 / 8;
    int lg = (t & 7) * CPX + (t >> 3);
    int mt = lg & 15;
    int nt = lg >> 4;                        // [0,128)
    gemm_body<0, 2048, I_, 2048, 1>(smem, mt, nt, 0, T_,
        xb, nullptr, ws1t, y1, nullptr, nullptr, nullptr);
  }
}

// ---------------- fused dispatch B: gemm3 (expert-down) ∥ gemm1 (shared-down) ----------------
__global__ __launch_bounds__(256) void fusedB_k(
    const bf16* __restrict__ y1, const bf16* __restrict__ ws2t,
    const bf16* __restrict__ act, const float* __restrict__ w2,
    float* __restrict__ scratch2, float* __restrict__ scratch,
    const int* __restrict__ tlist, const int* __restrict__ counts)
{
  __shared__ __align__(16) char smem[24576];
  if (blockIdx.x < 2048) {
    constexpr int NT = H_ / 64;              // 32
    constexpr int NWG = NT * E_ * 2;         // 2048
    constexpr int CPX = NWG / 8;
    int id = blockIdx.x;
    int lg = (id & 7) * CPX + (id >> 3);
    int bit = lg & 1;
    int en  = lg >> 1;
    int e  = en / NT;
    int nt = en % NT;
    int mt = (blockIdx.y == 0) ? bit : (2 + 2*((int)blockIdx.y - 1) + bit);
    int nrows = counts[e];
    if (mt * 128 >= nrows) return;
    gemm_body<3, M_, H_, M_, 1>(smem, mt, nt, 0, nrows,
        act, w2 + (size_t)e * M_ * H_, nullptr, nullptr, scratch, tlist + e*T_, nullptr);
  } else {
    int id = ((int)blockIdx.x - 2048) * 8 + (int)blockIdx.y;  // [0,1024)
    int kz  = id & 1;
    int sub = id >> 1;                       // [0,512)
    constexpr int CPX = 512 / 8;
    int lg = (sub & 7) * CPX + (sub >> 3);
    int mt = lg & 15;
    int nt = lg >> 4;                        // [0,32)
    gemm_body<1, I_, H_, I_, 2>(smem, mt, nt, kz, T_,
        y1, nullptr, ws2t, nullptr, scratch2, nullptr, nullptr);
  }
}

extern "C" void kernel_launch(void* const* d_in, const int* in_sizes, int n_in,
                              void* d_out, int out_size, void* d_ws, size_t ws_size,
                              hipStream_t stream) {
  const float* x   = (const float*)d_in[0];
  const float* gw  = (const float*)d_in[1];
  const float* w1  = (const float*)d_in[2];
  const float* w2  = (const float*)d_in[3];
  const float* ws1 = (const float*)d_in[4];
  const float* ws2 = (const float*)d_in[5];
  float* out    = (float*)d_out;
  float* logits = out + (size_t)T_ * H_;

  char* ws = (char*)d_ws;
  const size_t off_xb   = 0;
  const size_t off_y1   = off_xb  + (size_t)T_ * H_ * 2;
  const size_t off_act  = off_y1  + (size_t)T_ * I_ * 2;
  const size_t off_cnt  = off_act + (size_t)T_ * 4 * M_ * 2;
  const size_t off_tl   = off_cnt + 256;
  const size_t off_wl   = off_tl  + (size_t)E_ * T_ * 4;
  const size_t off_sc   = off_wl  + (size_t)E_ * T_ * 4;              // fp32 [4T][H]
  const size_t off_sc2  = off_sc  + (size_t)T_ * 4 * H_ * 4;          // fp32 [2][T][H]
  const size_t off_w1t  = off_sc2 + (size_t)2 * T_ * H_ * 4;          // bf16 ws1t [I][H]
  const size_t off_w2t  = off_w1t + (size_t)I_ * H_ * 2;              // bf16 ws2t [H][I]

  const bf16* xb = (const bf16*)(ws + off_xb);
  bf16* y1  = (bf16*)(ws + off_y1);
  bf16* act = (bf16*)(ws + off_act);
  int*  counts = (int*)(ws + off_cnt);
  int*  tlist  = (int*)(ws + off_tl);
  float* wlist = (float*)(ws + off_wl);
  float* scratch  = (float*)(ws + off_sc);
  float* scratch2 = (float*)(ws + off_sc2);
  bf16* ws1t = (bf16*)(ws + off_w1t);
  bf16* ws2t = (bf16*)(ws + off_w2t);

  prep_k<<<1, 64, 0, stream>>>(counts);
  tconv_k<<<dim3(H_/64, I_/64), 256, 0, stream>>>(ws1, ws1t, H_, I_);
  tconv_k<<<dim3(I_/64, H_/64), 256, 0, stream>>>(ws2, ws2t, I_, H_);
  router_k<<<T_, 64, 0, stream>>>(x, gw, logits, counts, tlist, wlist,
                                  (unsigned short*)(ws + off_xb));

  fusedA_k<<<dim3(1408 + 256, 8), 256, 0, stream>>>(
      xb, w1, ws1t, act, y1, tlist, wlist, counts);
  fusedB_k<<<dim3(2048 + 128, 8), 256, 0, stream>>>(
      y1, ws2t, act, w2, scratch2, scratch, tlist, counts);
  combine_k<<<4096, 256, 0, stream>>>(scratch, scratch2, out);
}

// Round 19
// 716.895 us; speedup vs baseline: 1.0465x; 1.0060x over previous
//
#include <hip/hip_runtime.h>

#define H_ 2048
#define E_ 32
#define KSEL 4
#define M_ 1408
#define I_ 8192
#define T_ 2048

typedef __bf16 bf16;
typedef bf16 bf16x8 __attribute__((ext_vector_type(8)));
typedef float f32x4 __attribute__((ext_vector_type(4)));
typedef unsigned short u16x8 __attribute__((ext_vector_type(8)));
typedef unsigned int u32x4 __attribute__((ext_vector_type(4)));

static __device__ __forceinline__ unsigned short bfb(float f) {
  return __builtin_bit_cast(unsigned short, (bf16)f);
}

static __device__ __forceinline__ void gload_lds16(const void* g, void* l) {
  __builtin_amdgcn_global_load_lds((const __attribute__((address_space(1))) void*)g,
                                   (__attribute__((address_space(3))) void*)l, 16, 0, 0);
}

static __device__ __forceinline__ float silu_f(float v) {
  return v / (1.f + __expf(-v));
}

static __device__ __forceinline__ void wave_argmax(float& v, int& vi) {
  #pragma unroll
  for (int off = 32; off >= 1; off >>= 1) {
    float ov = __shfl_xor(v, off);
    int   oi = __shfl_xor(vi, off);
    if (ov > v || (ov == v && oi < vi)) { v = ov; vi = oi; }
  }
}

// ---------------- combine: out = 4 routed-slot slices + 2 shared-kz slices ----------------
__global__ __launch_bounds__(256) void combine_k(const float* __restrict__ sc,
                                                 const float* __restrict__ sc2,
                                                 float* __restrict__ out) {
  size_t i = ((size_t)blockIdx.x * 256 + threadIdx.x) * 4;
  int t = (int)(i >> 11);
  int h = (int)(i & 2047);
  const float* s = sc + (size_t)(t * 4) * H_ + h;
  float4 a = *(const float4*)(s);
  float4 b = *(const float4*)(s + H_);
  float4 c = *(const float4*)(s + 2 * H_);
  float4 d = *(const float4*)(s + 3 * H_);
  float4 o;
  o.x = a.x + b.x + c.x + d.x;
  o.y = a.y + b.y + c.y + d.y;
  o.z = a.z + b.z + c.z + d.z;
  o.w = a.w + b.w + c.w + d.w;
  #pragma unroll
  for (int kz = 0; kz < 2; ++kz) {
    float4 v = *(const float4*)(sc2 + (size_t)kz * T_ * H_ + i);
    o.x += v.x; o.y += v.y; o.z += v.z; o.w += v.w;
  }
  *(float4*)(out + i) = o;
}

// ---------------- fused prologue: tconv(ws1) | tconv(ws2) | router(+cvt) ----------------
// bx < 4096: tconv ws1 tile; bx < 8192: tconv ws2 tile; else router, 4 waves =
// 4 independent tokens per block (router code is wave-local; no cross-wave sync).
// counts zeroed by hipMemsetAsync before this kernel.
static __device__ __forceinline__ void tconv_body(const float* __restrict__ src,
                                                  bf16* __restrict__ dst,
                                                  int K, int N, int kx, int ny) {
  __shared__ bf16 lt[64][66];
  const int t = threadIdx.x;
  const int k0 = kx * 64, n0 = ny * 64;
  #pragma unroll
  for (int p = 0; p < 4; ++p) {
    int r = p * 16 + (t >> 4);
    int c = (t & 15) * 4;
    float4 v = *(const float4*)(src + (size_t)(k0 + r) * N + n0 + c);
    lt[c+0][r] = (bf16)v.x; lt[c+1][r] = (bf16)v.y;
    lt[c+2][r] = (bf16)v.z; lt[c+3][r] = (bf16)v.w;
  }
  __syncthreads();
  #pragma unroll
  for (int q = 0; q < 2; ++q) {
    int n  = q * 32 + (t >> 3);
    int ks = (t & 7) * 8;
    bf16x8 o;
    #pragma unroll
    for (int j = 0; j < 8; ++j) o[j] = lt[n][ks + j];
    *(bf16x8*)(dst + (size_t)(n0 + n) * K + k0 + ks) = o;
  }
}

__global__ __launch_bounds__(256) void prologue_k(
    const float* __restrict__ x, const float* __restrict__ gw,
    const float* __restrict__ ws1, const float* __restrict__ ws2,
    bf16* __restrict__ ws1t, bf16* __restrict__ ws2t,
    float* __restrict__ logits, int* __restrict__ counts,
    int* __restrict__ tlist, float* __restrict__ wlist,
    unsigned short* __restrict__ xb)
{
  const int bx = blockIdx.x;
  if (bx < 4096) {                       // ws1: K=H (32 k-tiles), N=I (128 n-tiles)
    tconv_body(ws1, ws1t, H_, I_, bx & 31, bx >> 5);
    return;
  }
  if (bx < 8192) {                       // ws2: K=I (128 k-tiles), N=H (32 n-tiles)
    int id = bx - 4096;
    tconv_body(ws2, ws2t, I_, H_, id & 127, id >> 7);
    return;
  }
  // router: token per wave
  const int l = threadIdx.x & 63;
  const int t = (bx - 8192) * 4 + (threadIdx.x >> 6);

  {
    const float* xrow = x + (size_t)t * H_;
    unsigned short* xbrow = xb + (size_t)t * H_;
    #pragma unroll
    for (int j = 0; j < 4; ++j) {
      int base = j * 512 + l * 8;
      float4 a = *(const float4*)(xrow + base);
      float4 b = *(const float4*)(xrow + base + 4);
      u16x8 o;
      o[0]=bfb(a.x); o[1]=bfb(a.y); o[2]=bfb(a.z); o[3]=bfb(a.w);
      o[4]=bfb(b.x); o[5]=bfb(b.y); o[6]=bfb(b.z); o[7]=bfb(b.w);
      *(u16x8*)(xbrow + base) = o;
    }
  }

  int e = l & 31;
  int half = l >> 5;
  const float* xr = x + (size_t)t * H_ + half * (H_/2);
  const float* g  = gw + (size_t)(half * (H_/2)) * E_ + e;
  float a0=0.f, a1=0.f, a2=0.f, a3=0.f;
  for (int h = 0; h < H_/2; h += 4) {
    a0 = fmaf(xr[h],   g[(size_t)h*E_],     a0);
    a1 = fmaf(xr[h+1], g[(size_t)(h+1)*E_], a1);
    a2 = fmaf(xr[h+2], g[(size_t)(h+2)*E_], a2);
    a3 = fmaf(xr[h+3], g[(size_t)(h+3)*E_], a3);
  }
  float acc = (a0+a1)+(a2+a3);
  acc += __shfl_xor(acc, 32);
  if (l < E_) logits[(size_t)t*E_ + l] = acc;

  float cur = (l < E_) ? acc : -INFINITY;
  int myidx = (l < E_) ? e : 1000;
  float tv0,tv1,tv2,tv3; int ti0,ti1,ti2,ti3;
  { float v=cur; int vi=myidx; wave_argmax(v,vi); tv0=v; ti0=vi; if (myidx==vi) cur=-INFINITY; }
  { float v=cur; int vi=myidx; wave_argmax(v,vi); tv1=v; ti1=vi; if (myidx==vi) cur=-INFINITY; }
  { float v=cur; int vi=myidx; wave_argmax(v,vi); tv2=v; ti2=vi; if (myidx==vi) cur=-INFINITY; }
  { float v=cur; int vi=myidx; wave_argmax(v,vi); tv3=v; ti3=vi; }
  float w0 = 1.f;
  float w1 = __expf(tv1 - tv0);
  float w2 = __expf(tv2 - tv0);
  float w3 = __expf(tv3 - tv0);
  float inv = 1.f / (w0+w1+w2+w3);
  if (l < KSEL) {
    float myw = ((l==0)?w0:(l==1)?w1:(l==2)?w2:w3) * inv;
    int   myi = ((l==0)?ti0:(l==1)?ti1:(l==2)?ti2:ti3);
    int pos = atomicAdd(&counts[myi], 1);
    tlist[myi*T_ + pos] = (t << 2) | l;
    wlist[myi*T_ + pos] = myw;
  }
}

// ---------------- GEMM body (BK=64, BM=128, BN=64, r13-verified 2-barrier drain) ----------------
// Dense modes (0,1): BOTH operands bf16 via global_load_lds (Btp = bf16 [N,K]),
// same slot^(row&7) both-sides swizzle for A and B; loop = bar; DMA; bar; MFMA.
// Routed modes (2,3): B reg-staged from fp32 [K,N] with T14 prefetch (r13 loop).
template<int MODE, int KDIM, int NDIM, int ASTR, int KSPLIT>
__device__ __forceinline__ void gemm_body(
    char* __restrict__ smem, int mt, int nt, int kz, int nrows,
    const bf16* __restrict__ A, const float* __restrict__ Bp, const bf16* __restrict__ Btp,
    bf16* __restrict__ Cb, float* __restrict__ Cf,
    const int* __restrict__ lst, const float* __restrict__ wl)
{
  char* As = smem;            // 128 rows x 64 k bf16 (128B rows, 8 slots, swizzled)
  char* Bs = smem + 16384;    // dense: 64 rows x 128B (swizzled) | routed: slot-major [8][64][16B]
  const int tid = threadIdx.x;
  const int mrow0 = mt*128, ncol0 = nt*64;

  const bf16* abase[4];
  int aoffs[4];
  #pragma unroll
  for (int c = 0; c < 4; ++c) {
    int lidx = c*256 + tid;
    int row  = lidx >> 3;
    int slot = lidx & 7;
    aoffs[c] = (slot ^ (row & 7)) * 8;
    int ri = mrow0 + row;
    if constexpr (MODE == 2) {
      int tt = (ri < nrows) ? (lst[ri] >> 2) : 0;
      abase[c] = A + (size_t)tt * ASTR;
    } else if constexpr (MODE == 3) {
      int ar = (ri < nrows) ? lst[ri] : 0;
      abase[c] = A + (size_t)ar * ASTR;
    } else {
      abase[c] = A + (size_t)ri * ASTR;
    }
  }

  // dense B DMA bases (bf16 [N,K])
  const bf16* bbaseB[2];
  int boffs[2];
  if constexpr (MODE <= 1) {
    #pragma unroll
    for (int c = 0; c < 2; ++c) {
      int lidx = c*256 + tid;
      int row  = lidx >> 3;
      int slot = lidx & 7;
      boffs[c] = (slot ^ (row & 7)) * 8;
      bbaseB[c] = Btp + (size_t)(ncol0 + row) * KDIM;
    }
  }

  // routed B reg-staging partition
  const int bn = tid & 63;
  const int bq = tid >> 6;
  const float* bsrc0 = Bp + (size_t)(bq * 16) * NDIM + ncol0 + bn;
  char* const bdst = Bs + (bq*2)*1024 + bn*16;

  const int l  = tid & 63;
  const int wv = tid >> 6;
  const int wr = wv >> 1, wc = wv & 1;
  const int ss = l >> 4;

  f32x4 acc[4][2] = {};

  constexpr int ITERS = KDIM / 64 / KSPLIT;
  static_assert(ITERS % 2 == 0, "K-loop is 2-unrolled");
  const int kt0 = kz * ITERS;
  const int ktend = kt0 + ITERS;

  float vA[16], vB[16];   // constant-indexed only (full unroll) -> registers

#define LOADB(P, KT) do {                                            \
    const float* bs_ = bsrc0 + (size_t)((KT) * 64) * NDIM;           \
    _Pragma("unroll")                                                \
    for (int j = 0; j < 16; ++j) P[j] = bs_[(size_t)j * NDIM];       \
  } while (0)

#define WRITEB(P) do {                                               \
    u32x4 lo_, hi_;                                                  \
    _Pragma("unroll")                                                \
    for (int j = 0; j < 4; ++j) {                                    \
      lo_[j] = (unsigned)bfb(P[2*j])   | ((unsigned)bfb(P[2*j+1]) << 16); \
      hi_[j] = (unsigned)bfb(P[8+2*j]) | ((unsigned)bfb(P[8+2*j+1]) << 16); \
    }                                                                \
    *(u32x4*)(bdst)        = lo_;                                    \
    *(u32x4*)(bdst + 1024) = hi_;                                    \
  } while (0)

#define MFMA_HALF(S) do {                                            \
    bf16x8 af[4], bfr[2];                                            \
    const int ks = (S)*4 + ss;                                       \
    _Pragma("unroll")                                                \
    for (int mf = 0; mf < 4; ++mf) {                                 \
      int r = wr*64 + mf*16 + (l & 15);                              \
      af[mf] = *(const bf16x8*)(As + r*128 + ((ks ^ (r & 7)) << 4)); \
    }                                                                \
    _Pragma("unroll")                                                \
    for (int nf = 0; nf < 2; ++nf) {                                 \
      int c = wc*32 + nf*16 + (l & 15);                              \
      if constexpr (MODE <= 1)                                       \
        bfr[nf] = *(const bf16x8*)(Bs + c*128 + ((ks ^ (c & 7)) << 4)); \
      else                                                           \
        bfr[nf] = *(const bf16x8*)(Bs + ks*1024 + c*16);             \
    }                                                                \
    _Pragma("unroll")                                                \
    for (int mf = 0; mf < 4; ++mf)                                   \
      _Pragma("unroll")                                              \
      for (int nf = 0; nf < 2; ++nf)                                 \
        acc[mf][nf] = __builtin_amdgcn_mfma_f32_16x16x32_bf16(af[mf], bfr[nf], acc[mf][nf], 0, 0, 0); \
  } while (0)

#define MFMA_PHASE() do { MFMA_HALF(0); MFMA_HALF(1); } while (0)

#define ADMA(KT) do {                                                \
    _Pragma("unroll")                                                \
    for (int c = 0; c < 4; ++c)                                      \
      gload_lds16(abase[c] + (KT)*64 + aoffs[c], As + (c*256 + tid)*16); \
  } while (0)

#define BDMA(KT) do {                                                \
    _Pragma("unroll")                                                \
    for (int c = 0; c < 2; ++c)                                      \
      gload_lds16(bbaseB[c] + (KT)*64 + boffs[c], Bs + (c*256 + tid)*16); \
  } while (0)

  if constexpr (MODE <= 1) {
    for (int kt = kt0; kt < ktend; ++kt) {
      __syncthreads();
      ADMA(kt);
      BDMA(kt);
      __syncthreads();
      MFMA_PHASE();
    }
  } else {
    LOADB(vA, kt0);
    for (int kt = kt0; kt < ktend; kt += 2) {
      __syncthreads();
      ADMA(kt);
      WRITEB(vA);
      __syncthreads();
      LOADB(vB, kt + 1);           // flies during MFMA phase
      MFMA_PHASE();

      __syncthreads();
      ADMA(kt + 1);
      WRITEB(vB);
      __syncthreads();
      if (kt + 2 < ktend) LOADB(vA, kt + 2);   // flies during MFMA phase
      MFMA_PHASE();
    }
  }

#undef LOADB
#undef WRITEB
#undef MFMA_HALF
#undef MFMA_PHASE
#undef ADMA
#undef BDMA

  // epilogue — C/D layout: row=(l>>4)*4+j, col=l&15 within each 16x16 frag
  #pragma unroll
  for (int mf = 0; mf < 4; ++mf) {
    #pragma unroll
    for (int j = 0; j < 4; ++j) {
      const int rloc = wr*64 + mf*16 + (l >> 4)*4 + j;
      const int grow = mrow0 + rloc;
      if constexpr (MODE == 0) {
        #pragma unroll
        for (int nf = 0; nf < 2; ++nf) {
          int col = ncol0 + wc*32 + nf*16 + (l & 15);
          Cb[(size_t)grow * NDIM + col] = (bf16)silu_f(acc[mf][nf][j]);
        }
      } else if constexpr (MODE == 1) {
        float* dst = Cf + (size_t)kz * T_ * H_;
        #pragma unroll
        for (int nf = 0; nf < 2; ++nf) {
          int col = ncol0 + wc*32 + nf*16 + (l & 15);
          dst[(size_t)grow * NDIM + col] = acc[mf][nf][j];
        }
      } else if constexpr (MODE == 2) {
        if (grow < nrows) {
          int entry = lst[grow];
          float wg = wl[grow];
          #pragma unroll
          for (int nf = 0; nf < 2; ++nf) {
            int col = ncol0 + wc*32 + nf*16 + (l & 15);
            Cb[(size_t)entry * NDIM + col] = (bf16)(silu_f(acc[mf][nf][j]) * wg);
          }
        }
      } else {
        if (grow < nrows) {
          int entry = lst[grow];
          #pragma unroll
          for (int nf = 0; nf < 2; ++nf) {
            int col = ncol0 + wc*32 + nf*16 + (l & 15);
            Cf[(size_t)entry * H_ + col] = acc[mf][nf][j];
          }
        }
      }
    }
  }
}

// ---------------- fused dispatch A: gemm2 (expert-up) ∥ gemm0 (shared-up) ----------------
__global__ __launch_bounds__(256) void fusedA_k(
    const bf16* __restrict__ xb, const float* __restrict__ w1, const bf16* __restrict__ ws1t,
    bf16* __restrict__ act, bf16* __restrict__ y1,
    const int* __restrict__ tlist, const float* __restrict__ wlist, const int* __restrict__ counts)
{
  __shared__ __align__(16) char smem[24576];
  if (blockIdx.x < 1408) {
    constexpr int NT = M_ / 64;              // 22
    constexpr int NWG = NT * E_ * 2;         // 1408
    constexpr int CPX = NWG / 8;
    int id = blockIdx.x;
    int lg = (id & 7) * CPX + (id >> 3);
    int bit = lg & 1;
    int en  = lg >> 1;
    int e  = en / NT;
    int nt = en % NT;
    int mt = (blockIdx.y == 0) ? bit : (2 + 2*((int)blockIdx.y - 1) + bit);
    int nrows = counts[e];
    if (mt * 128 >= nrows) return;
    gemm_body<2, 2048, M_, 2048, 1>(smem, mt, nt, 0, nrows,
        xb, w1 + (size_t)e * 2048 * M_, nullptr, act, nullptr, tlist + e*T_, wlist + e*T_);
  } else {
    int t = ((int)blockIdx.x - 1408) * 8 + (int)blockIdx.y;   // [0,2048)
    constexpr int CPX = 2048 / 8;
    int lg = (t & 7) * CPX + (t >> 3);
    int mt = lg & 15;
    int nt = lg >> 4;                        // [0,128)
    gemm_body<0, 2048, I_, 2048, 1>(smem, mt, nt, 0, T_,
        xb, nullptr, ws1t, y1, nullptr, nullptr, nullptr);
  }
}

// ---------------- fused dispatch B: gemm3 (expert-down) ∥ gemm1 (shared-down) ----------------
__global__ __launch_bounds__(256) void fusedB_k(
    const bf16* __restrict__ y1, const bf16* __restrict__ ws2t,
    const bf16* __restrict__ act, const float* __restrict__ w2,
    float* __restrict__ scratch2, float* __restrict__ scratch,
    const int* __restrict__ tlist, const int* __restrict__ counts)
{
  __shared__ __align__(16) char smem[24576];
  if (blockIdx.x < 2048) {
    constexpr int NT = H_ / 64;              // 32
    constexpr int NWG = NT * E_ * 2;         // 2048
    constexpr int CPX = NWG / 8;
    int id = blockIdx.x;
    int lg = (id & 7) * CPX + (id >> 3);
    int bit = lg & 1;
    int en  = lg >> 1;
    int e  = en / NT;
    int nt = en % NT;
    int mt = (blockIdx.y == 0) ? bit : (2 + 2*((int)blockIdx.y - 1) + bit);
    int nrows = counts[e];
    if (mt * 128 >= nrows) return;
    gemm_body<3, M_, H_, M_, 1>(smem, mt, nt, 0, nrows,
        act, w2 + (size_t)e * M_ * H_, nullptr, nullptr, scratch, tlist + e*T_, nullptr);
  } else {
    int id = ((int)blockIdx.x - 2048) * 8 + (int)blockIdx.y;  // [0,1024)
    int kz  = id & 1;
    int sub = id >> 1;                       // [0,512)
    constexpr int CPX = 512 / 8;
    int lg = (sub & 7) * CPX + (sub >> 3);
    int mt = lg & 15;
    int nt = lg >> 4;                        // [0,32)
    gemm_body<1, I_, H_, I_, 2>(smem, mt, nt, kz, T_,
        y1, nullptr, ws2t, nullptr, scratch2, nullptr, nullptr);
  }
}

extern "C" void kernel_launch(void* const* d_in, const int* in_sizes, int n_in,
                              void* d_out, int out_size, void* d_ws, size_t ws_size,
                              hipStream_t stream) {
  const float* x   = (const float*)d_in[0];
  const float* gw  = (const float*)d_in[1];
  const float* w1  = (const float*)d_in[2];
  const float* w2  = (const float*)d_in[3];
  const float* ws1 = (const float*)d_in[4];
  const float* ws2 = (const float*)d_in[5];
  float* out    = (float*)d_out;
  float* logits = out + (size_t)T_ * H_;

  char* ws = (char*)d_ws;
  const size_t off_xb   = 0;
  const size_t off_y1   = off_xb  + (size_t)T_ * H_ * 2;
  const size_t off_act  = off_y1  + (size_t)T_ * I_ * 2;
  const size_t off_cnt  = off_act + (size_t)T_ * 4 * M_ * 2;
  const size_t off_tl   = off_cnt + 256;
  const size_t off_wl   = off_tl  + (size_t)E_ * T_ * 4;
  const size_t off_sc   = off_wl  + (size_t)E_ * T_ * 4;              // fp32 [4T][H]
  const size_t off_sc2  = off_sc  + (size_t)T_ * 4 * H_ * 4;          // fp32 [2][T][H]
  const size_t off_w1t  = off_sc2 + (size_t)2 * T_ * H_ * 4;          // bf16 ws1t [I][H]
  const size_t off_w2t  = off_w1t + (size_t)I_ * H_ * 2;              // bf16 ws2t [H][I]

  const bf16* xb = (const bf16*)(ws + off_xb);
  bf16* y1  = (bf16*)(ws + off_y1);
  bf16* act = (bf16*)(ws + off_act);
  int*  counts = (int*)(ws + off_cnt);
  int*  tlist  = (int*)(ws + off_tl);
  float* wlist = (float*)(ws + off_wl);
  float* scratch  = (float*)(ws + off_sc);
  float* scratch2 = (float*)(ws + off_sc2);
  bf16* ws1t = (bf16*)(ws + off_w1t);
  bf16* ws2t = (bf16*)(ws + off_w2t);

  hipMemsetAsync(counts, 0, E_ * sizeof(int), stream);
  prologue_k<<<dim3(8192 + 512), 256, 0, stream>>>(
      x, gw, ws1, ws2, ws1t, ws2t, logits, counts, tlist, wlist,
      (unsigned short*)(ws + off_xb));

  fusedA_k<<<dim3(1408 + 256, 8), 256, 0, stream>>>(
      xb, w1, ws1t, act, y1, tlist, wlist, counts);
  fusedB_k<<<dim3(2048 + 128, 8), 256, 0, stream>>>(
      y1, ws2t, act, w2, scratch2, scratch, tlist, counts);
  combine_k<<<4096, 256, 0, stream>>>(scratch, scratch2, out);
}